// Round 1
// baseline (574.907 us; speedup 1.0000x reference)
//
#include <hip/hip_runtime.h>

#define B_ 4
#define N_ 1024
#define F_ 128
#define R_ 16
#define E_ 65536
#define BN_ 4096

// ---------------- psi1 aggregation: agg[dst] += x[src], F=128 ----------------
__global__ __launch_bounds__(256) void scatter_f(
    const float* __restrict__ xs, const int* __restrict__ eis, float* __restrict__ aggs,
    const float* __restrict__ xt, const int* __restrict__ eit, float* __restrict__ aggt) {
  const float* x  = blockIdx.y ? xt  : xs;
  const int*  ei  = blockIdx.y ? eit : eis;
  float*      agg = blockIdx.y ? aggt : aggs;
  int gid = blockIdx.x * 256 + threadIdx.x;       // E*32 threads, 4 floats each
  int e = gid >> 5, c = (gid & 31) * 4;
  int src = ei[e], dst = ei[E_ + e];
  const float4 v = *(const float4*)(x + (size_t)src * F_ + c);
  float* p = agg + (size_t)dst * F_ + c;
  atomicAdd(p + 0, v.x); atomicAdd(p + 1, v.y);
  atomicAdd(p + 2, v.z); atomicAdd(p + 3, v.w);
}

// ------------- h = relu(x@Ws + agg@Wn + b), M=4096 N=128 K=128x2 -------------
// 64x64 tile, 256 threads, 4x4 micro-tile, LDS A transposed for float4 reads
__global__ __launch_bounds__(256) void psi1_gemm(
    const float* __restrict__ xs, const float* __restrict__ aggs,
    const float* __restrict__ xt, const float* __restrict__ aggt,
    const float* __restrict__ Ws, const float* __restrict__ Wn,
    const float* __restrict__ bias, float* __restrict__ hs, float* __restrict__ ht) {
  const float* x   = blockIdx.z ? xt   : xs;
  const float* agg = blockIdx.z ? aggt : aggs;
  float*       h   = blockIdx.z ? ht   : hs;
  int n0 = blockIdx.x * 64, m0 = blockIdx.y * 64;
  int tid = threadIdx.x, tx = tid & 15, ty = tid >> 4;
  __shared__ __align__(16) float sA[16][68];
  __shared__ __align__(16) float sB[16][68];
  float acc[4][4] = {};
  for (int phase = 0; phase < 2; phase++) {
    const float* A  = phase ? agg : x;
    const float* Bw = phase ? Wn  : Ws;
    for (int kb = 0; kb < F_; kb += 16) {
      int row = tid >> 2, k4 = (tid & 3) * 4;
      float4 va = *(const float4*)(A + (size_t)(m0 + row) * F_ + kb + k4);
      sA[k4 + 0][row] = va.x; sA[k4 + 1][row] = va.y;
      sA[k4 + 2][row] = va.z; sA[k4 + 3][row] = va.w;
      int k = tid >> 4, n4 = (tid & 15) * 4;
      *(float4*)&sB[k][n4] = *(const float4*)(Bw + (size_t)(kb + k) * F_ + n0 + n4);
      __syncthreads();
#pragma unroll
      for (int kk = 0; kk < 16; kk++) {
        float a[4], bb[4];
        *(float4*)a  = *(const float4*)&sA[kk][ty * 4];
        *(float4*)bb = *(const float4*)&sB[kk][tx * 4];
#pragma unroll
        for (int i = 0; i < 4; i++)
#pragma unroll
          for (int j = 0; j < 4; j++) acc[i][j] += a[i] * bb[j];
      }
      __syncthreads();
    }
  }
  float4 bv = *(const float4*)(bias + n0 + tx * 4);
  float bj[4] = {bv.x, bv.y, bv.z, bv.w};
#pragma unroll
  for (int i = 0; i < 4; i++) {
    int m = m0 + ty * 4 + i;
    float4 o;
    o.x = fmaxf(acc[i][0] + bj[0], 0.f); o.y = fmaxf(acc[i][1] + bj[1], 0.f);
    o.z = fmaxf(acc[i][2] + bj[2], 0.f); o.w = fmaxf(acc[i][3] + bj[3], 0.f);
    *(float4*)(h + (size_t)m * F_ + n0 + tx * 4) = o;
  }
}

// ---------- S_hat[b] = h_s[b] @ h_t[b]^T  (NT), 128x128 tile, 8x8 micro ----------
__global__ __launch_bounds__(256) void shat_gemm(
    const float* __restrict__ hs, const float* __restrict__ ht, float* __restrict__ S) {
  int b = blockIdx.z;
  int n0 = blockIdx.x * 128, m0 = blockIdx.y * 128;
  int tid = threadIdx.x, tx = tid & 15, ty = tid >> 4;
  __shared__ __align__(16) float sA[16][132];
  __shared__ __align__(16) float sB[16][132];
  float acc[8][8] = {};
  const float* Ag = hs + (size_t)(b * N_ + m0) * F_;
  const float* Bg = ht + (size_t)(b * N_ + n0) * F_;
  for (int kb = 0; kb < F_; kb += 16) {
#pragma unroll
    for (int l = 0; l < 2; l++) {
      int idx = tid + l * 256;                  // 0..511
      int row = idx >> 2, k4 = (idx & 3) * 4;
      float4 va = *(const float4*)(Ag + (size_t)row * F_ + kb + k4);
      sA[k4 + 0][row] = va.x; sA[k4 + 1][row] = va.y;
      sA[k4 + 2][row] = va.z; sA[k4 + 3][row] = va.w;
      float4 vb = *(const float4*)(Bg + (size_t)row * F_ + kb + k4);
      sB[k4 + 0][row] = vb.x; sB[k4 + 1][row] = vb.y;
      sB[k4 + 2][row] = vb.z; sB[k4 + 3][row] = vb.w;
    }
    __syncthreads();
#pragma unroll
    for (int kk = 0; kk < 16; kk++) {
      float a[8], bb[8];
      *(float4*)&a[0]  = *(const float4*)&sA[kk][ty * 8];
      *(float4*)&a[4]  = *(const float4*)&sA[kk][ty * 8 + 4];
      *(float4*)&bb[0] = *(const float4*)&sB[kk][tx * 8];
      *(float4*)&bb[4] = *(const float4*)&sB[kk][tx * 8 + 4];
#pragma unroll
      for (int i = 0; i < 8; i++)
#pragma unroll
        for (int j = 0; j < 8; j++) acc[i][j] += a[i] * bb[j];
    }
    __syncthreads();
  }
#pragma unroll
  for (int i = 0; i < 8; i++) {
    size_t off = ((size_t)(b * N_ + m0 + ty * 8 + i)) * N_ + n0 + tx * 8;
    float4 o0 = {acc[i][0], acc[i][1], acc[i][2], acc[i][3]};
    float4 o1 = {acc[i][4], acc[i][5], acc[i][6], acc[i][7]};
    *(float4*)(S + off) = o0; *(float4*)(S + off + 4) = o1;
  }
}

// ---------------- row softmax over N=1024, one block per row ----------------
__global__ __launch_bounds__(256) void softmax_row(
    const float* __restrict__ in, float* __restrict__ out) {
  int row = blockIdx.x;
  float4 v = ((const float4*)(in + (size_t)row * N_))[threadIdx.x];
  float m = fmaxf(fmaxf(v.x, v.y), fmaxf(v.z, v.w));
#pragma unroll
  for (int o = 32; o > 0; o >>= 1) m = fmaxf(m, __shfl_down(m, o, 64));
  __shared__ float rmax[4], rsum[4];
  int wave = threadIdx.x >> 6, lane = threadIdx.x & 63;
  if (lane == 0) rmax[wave] = m;
  __syncthreads();
  m = fmaxf(fmaxf(rmax[0], rmax[1]), fmaxf(rmax[2], rmax[3]));
  float e0 = __expf(v.x - m), e1 = __expf(v.y - m);
  float e2 = __expf(v.z - m), e3 = __expf(v.w - m);
  float s = e0 + e1 + e2 + e3;
#pragma unroll
  for (int o = 32; o > 0; o >>= 1) s += __shfl_down(s, o, 64);
  if (lane == 0) rsum[wave] = s;
  __syncthreads();
  s = rsum[0] + rsum[1] + rsum[2] + rsum[3];
  float inv = 1.f / s;
  float4 o4 = {e0 * inv, e1 * inv, e2 * inv, e3 * inv};
  ((float4*)(out + (size_t)row * N_))[threadIdx.x] = o4;
}

// ------------- r_t[b,t,r] = sum_s S[b,s,t]*r_s[b,s,r]  (atomic over s-chunks) -------------
__global__ __launch_bounds__(256) void rt_gemm(
    const float* __restrict__ S, const float* __restrict__ rs, float* __restrict__ rt) {
  int b = blockIdx.z, s0 = blockIdx.y * 128, t0 = blockIdx.x * 64;
  int tid = threadIdx.x, tl = tid & 63, rg = tid >> 6;
  __shared__ __align__(16) float rsh[128][17];
  for (int i = tid; i < 512; i += 256) {
    int srow = i >> 2, c = (i & 3) * 4;
    float4 v = *(const float4*)(rs + ((size_t)(b * N_ + s0 + srow)) * R_ + c);
    rsh[srow][c] = v.x; rsh[srow][c + 1] = v.y;
    rsh[srow][c + 2] = v.z; rsh[srow][c + 3] = v.w;
  }
  __syncthreads();
  float a0 = 0, a1 = 0, a2 = 0, a3 = 0;
  const float* Sp = S + ((size_t)(b * N_ + s0)) * N_ + t0 + tl;
  int rb = rg * 4;
  for (int s = 0; s < 128; s++) {
    float sv = Sp[(size_t)s * N_];
    a0 += sv * rsh[s][rb + 0]; a1 += sv * rsh[s][rb + 1];
    a2 += sv * rsh[s][rb + 2]; a3 += sv * rsh[s][rb + 3];
  }
  float* o = rt + ((size_t)(b * N_ + t0 + tl)) * R_ + rb;
  atomicAdd(o + 0, a0); atomicAdd(o + 1, a1);
  atomicAdd(o + 2, a2); atomicAdd(o + 3, a3);
}

// ---------------- psi2 aggregation, R=16 ----------------
__global__ __launch_bounds__(256) void scatter_r(
    const float* __restrict__ rs, const int* __restrict__ eis, float* __restrict__ aggs,
    const float* __restrict__ rtv, const int* __restrict__ eit, float* __restrict__ aggt) {
  const float* v  = blockIdx.y ? rtv : rs;
  const int*  ei  = blockIdx.y ? eit : eis;
  float*      agg = blockIdx.y ? aggt : aggs;
  int gid = blockIdx.x * 256 + threadIdx.x;       // E*4 threads
  int e = gid >> 2, c = (gid & 3) * 4;
  int src = ei[e], dst = ei[E_ + e];
  const float4 x = *(const float4*)(v + (size_t)src * R_ + c);
  float* p = agg + (size_t)dst * R_ + c;
  atomicAdd(p + 0, x.x); atomicAdd(p + 1, x.y);
  atomicAdd(p + 2, x.z); atomicAdd(p + 3, x.w);
}

// ------- P = relu(v@W2s + agg@W2n + b2) @ Wm1, rows of 16, R=16 -------
__global__ __launch_bounds__(256) void psi2p(
    const float* __restrict__ vs, const float* __restrict__ aggs_,
    const float* __restrict__ vt, const float* __restrict__ aggt_,
    const float* __restrict__ W2s, const float* __restrict__ W2n,
    const float* __restrict__ b2, const float* __restrict__ Wm1,
    float* __restrict__ Ps, float* __restrict__ Pt) {
  const float* v   = blockIdx.y ? vt    : vs;
  const float* agg = blockIdx.y ? aggt_ : aggs_;
  float*       P   = blockIdx.y ? Pt    : Ps;
  int col = threadIdx.x & 15, row = threadIdx.x >> 4;
  int r0 = blockIdx.x * 16;
  __shared__ float sWs[16][16], sWn[16][16], sWm[16][17];
  __shared__ float sv[16][17], sa[16][17], so[16][17];
  sWs[row][col] = W2s[row * 16 + col];
  sWn[row][col] = W2n[row * 16 + col];
  sWm[row][col] = Wm1[row * 16 + col];
  sv[row][col] = v[(size_t)(r0 + row) * R_ + col];
  sa[row][col] = agg[(size_t)(r0 + row) * R_ + col];
  __syncthreads();
  float o = b2[col];
#pragma unroll
  for (int k = 0; k < 16; k++) o += sv[row][k] * sWs[k][col] + sa[row][k] * sWn[k][col];
  so[row][col] = fmaxf(o, 0.f);
  __syncthreads();
  float p = 0;
#pragma unroll
  for (int k = 0; k < 16; k++) p += so[row][k] * sWm[k][col];
  P[(size_t)(r0 + row) * R_ + col] = p;
}

// ---- S_hat[b,s,t] += sum_r relu(Ps[b,s,r]-Pt[b,t,r]+bm1[r])*Wm2[r] + bm2 ----
// block: 256 t-lanes x 4 s rows
__global__ __launch_bounds__(256) void upd_kernel(
    float* __restrict__ Shat, const float* __restrict__ Ps, const float* __restrict__ Pt,
    const float* __restrict__ bm1, const float* __restrict__ Wm2,
    const float* __restrict__ bm2) {
  int b = blockIdx.z, s0 = blockIdx.y * 4, t0 = blockIdx.x * 256;
  int tid = threadIdx.x;
  __shared__ float pt[256][17];
  __shared__ float ps[4][16];
  __shared__ float sb[16], sw[16];
  for (int i = tid; i < 1024; i += 256) {
    int tr = i >> 2, c = (i & 3) * 4;
    const float4 v = *(const float4*)(Pt + ((size_t)(b * N_ + t0 + tr)) * R_ + c);
    pt[tr][c] = v.x; pt[tr][c + 1] = v.y; pt[tr][c + 2] = v.z; pt[tr][c + 3] = v.w;
  }
  if (tid < 64) ps[tid >> 4][tid & 15] = Ps[((size_t)(b * N_ + s0 + (tid >> 4))) * R_ + (tid & 15)];
  if (tid < 16) { sb[tid] = bm1[tid]; sw[tid] = Wm2[tid]; }
  __syncthreads();
  float bm2v = bm2[0];
  float ptl[16];
#pragma unroll
  for (int r = 0; r < 16; r++) ptl[r] = pt[tid][r];
#pragma unroll
  for (int si = 0; si < 4; si++) {
    size_t off = ((size_t)(b * N_ + s0 + si)) * N_ + t0 + tid;
    float sum = bm2v;
#pragma unroll
    for (int r = 0; r < 16; r++) sum += fmaxf(ps[si][r] - ptl[r] + sb[r], 0.f) * sw[r];
    Shat[off] += sum;
  }
}

extern "C" void kernel_launch(void* const* d_in, const int* in_sizes, int n_in,
                              void* d_out, int out_size, void* d_ws, size_t ws_size,
                              hipStream_t stream) {
  const float* x_s = (const float*)d_in[0];
  const int*   ei_s = (const int*)d_in[1];
  const float* x_t = (const float*)d_in[2];
  const int*   ei_t = (const int*)d_in[3];
  const float* W1s = (const float*)d_in[4];
  const float* W1n = (const float*)d_in[5];
  const float* b1  = (const float*)d_in[6];
  const float* W2s = (const float*)d_in[7];
  const float* W2n = (const float*)d_in[8];
  const float* b2  = (const float*)d_in[9];
  const float* Wm1 = (const float*)d_in[10];
  const float* bm1 = (const float*)d_in[11];
  const float* Wm2 = (const float*)d_in[12];
  const float* bm2 = (const float*)d_in[13];
  const float* r_steps = (const float*)d_in[14];

  float* out = (float*)d_out;
  float* S0 = out;                         // [4,1024,1024]
  float* SL = out + (size_t)B_ * N_ * N_;  // [4,1024,1024] (also scratch for step-1 S)

  float* ws = (float*)d_ws;
  float* agg_s = ws;                       // 524288
  float* agg_t = ws + 524288;              // 524288
  float* h_s   = ws + 1048576;             // 524288
  float* h_t   = ws + 1572864;             // 524288
  float* Shat  = ws + 2097152;             // 4194304
  float* rtb   = ws + 6291456;             // 65536
  float* agg2s = ws + 6356992;             // 65536
  float* agg2t = ws + 6422528;             // 65536
  float* Ps    = ws + 6488064;             // 65536
  float* Pt    = ws + 6553600;             // 65536

  // psi1 on both graphs
  hipMemsetAsync(agg_s, 0, 2 * 524288 * sizeof(float), stream);
  scatter_f<<<dim3(8192, 2), 256, 0, stream>>>(x_s, ei_s, agg_s, x_t, ei_t, agg_t);
  psi1_gemm<<<dim3(2, 64, 2), 256, 0, stream>>>(x_s, agg_s, x_t, agg_t, W1s, W1n, b1, h_s, h_t);

  // S_hat and S_0
  shat_gemm<<<dim3(8, 8, 4), 256, 0, stream>>>(h_s, h_t, Shat);
  softmax_row<<<B_ * N_, 256, 0, stream>>>(Shat, S0);

  for (int step = 0; step < 2; step++) {
    const float* rs = r_steps + (size_t)step * B_ * N_ * R_;
    const float* Scur;
    if (step == 0) {
      Scur = S0;  // softmax(S_hat) at step 0 is exactly S_0
    } else {
      softmax_row<<<B_ * N_, 256, 0, stream>>>(Shat, SL);  // SL region as scratch
      Scur = SL;
    }
    hipMemsetAsync(rtb, 0, 3 * 65536 * sizeof(float), stream);  // rtb, agg2s, agg2t
    rt_gemm<<<dim3(16, 8, 4), 256, 0, stream>>>(Scur, rs, rtb);
    scatter_r<<<dim3(1024, 2), 256, 0, stream>>>(rs, ei_s, agg2s, rtb, ei_t, agg2t);
    psi2p<<<dim3(256, 2), 256, 0, stream>>>(rs, agg2s, rtb, agg2t, W2s, W2n, b2, Wm1, Ps, Pt);
    upd_kernel<<<dim3(4, 256, 4), 256, 0, stream>>>(Shat, Ps, Pt, bm1, Wm2, bm2);
  }

  // final S_L
  softmax_row<<<B_ * N_, 256, 0, stream>>>(Shat, SL);
}

// Round 2
// 336.008 us; speedup vs baseline: 1.7110x; 1.7110x over previous
//
#include <hip/hip_runtime.h>

#define B_ 4
#define N_ 1024
#define F_ 128
#define R_ 16
#define E_ 65536
#define BN_ 4096

// ---------------- CSR build: histogram of dst ----------------
__global__ __launch_bounds__(256) void hist_k(
    const int* __restrict__ eis, const int* __restrict__ eit, int* __restrict__ counts) {
  const int* ei = blockIdx.y ? eit : eis;
  int* c = counts + blockIdx.y * BN_;
  int e = blockIdx.x * 256 + threadIdx.x;
  atomicAdd(c + ei[E_ + e], 1);
}

// ---------------- CSR build: exclusive scan (4096 = 256 threads x 16) ----------------
__global__ __launch_bounds__(256) void csr_scan(
    const int* __restrict__ counts, int* __restrict__ offs, int* __restrict__ cursor) {
  const int* c = counts + blockIdx.x * BN_;
  int* o = offs + blockIdx.x * (BN_ + 1);
  int* cur = cursor + blockIdx.x * BN_;
  int tid = threadIdx.x;
  int base = tid * 16;
  int local[16], sum = 0;
#pragma unroll
  for (int i = 0; i < 16; i++) { local[i] = sum; sum += c[base + i]; }
  __shared__ int csum[256];
  csum[tid] = sum;
  __syncthreads();
  for (int d = 1; d < 256; d <<= 1) {
    int v = (tid >= d) ? csum[tid - d] : 0;
    __syncthreads();
    csum[tid] += v;
    __syncthreads();
  }
  int prev = (tid == 0) ? 0 : csum[tid - 1];
#pragma unroll
  for (int i = 0; i < 16; i++) { int off = prev + local[i]; o[base + i] = off; cur[base + i] = off; }
  if (tid == 255) o[BN_] = csum[255];
}

// ---------------- CSR build: fill src lists ----------------
__global__ __launch_bounds__(256) void csr_fill(
    const int* __restrict__ eis, const int* __restrict__ eit,
    int* __restrict__ cursor, int* __restrict__ csr) {
  const int* ei = blockIdx.y ? eit : eis;
  int* cur = cursor + blockIdx.y * BN_;
  int* cs = csr + blockIdx.y * E_;
  int e = blockIdx.x * 256 + threadIdx.x;
  int src = ei[e], dst = ei[E_ + e];
  int pos = atomicAdd(cur + dst, 1);
  cs[pos] = src;
}

// ---------------- psi1 aggregation via gather: agg[n] = sum_{src in csr[n]} x[src] ----------------
// 256 threads = 2 nodes x 128 channels
__global__ __launch_bounds__(256) void gather_f(
    const float* __restrict__ xs, const float* __restrict__ xt,
    const int* __restrict__ csr, const int* __restrict__ offs,
    float* __restrict__ aggs, float* __restrict__ aggt) {
  const float* x = blockIdx.y ? xt : xs;
  const int* cs = csr + blockIdx.y * E_;
  const int* of = offs + blockIdx.y * (BN_ + 1);
  float* agg = blockIdx.y ? aggt : aggs;
  int node = blockIdx.x * 2 + (threadIdx.x >> 7);
  int ch = threadIdx.x & 127;
  int j0 = of[node], j1 = of[node + 1];
  float acc = 0.f, acc2 = 0.f;
  int j = j0;
  for (; j + 1 < j1; j += 2) {
    int s0 = cs[j], s1 = cs[j + 1];
    acc  += x[(size_t)s0 * F_ + ch];
    acc2 += x[(size_t)s1 * F_ + ch];
  }
  if (j < j1) acc += x[(size_t)cs[j] * F_ + ch];
  agg[(size_t)node * F_ + ch] = acc + acc2;
}

// ---------------- psi2 aggregation via gather, R=16: 256 threads = 16 nodes x 16 ch ----------------
__global__ __launch_bounds__(256) void gather_r(
    const float* __restrict__ rs, const float* __restrict__ rtv,
    const int* __restrict__ csr, const int* __restrict__ offs,
    float* __restrict__ aggs, float* __restrict__ aggt) {
  const float* v = blockIdx.y ? rtv : rs;
  const int* cs = csr + blockIdx.y * E_;
  const int* of = offs + blockIdx.y * (BN_ + 1);
  float* agg = blockIdx.y ? aggt : aggs;
  int node = blockIdx.x * 16 + (threadIdx.x >> 4);
  int ch = threadIdx.x & 15;
  int j0 = of[node], j1 = of[node + 1];
  float acc = 0.f, acc2 = 0.f;
  int j = j0;
  for (; j + 1 < j1; j += 2) {
    int s0 = cs[j], s1 = cs[j + 1];
    acc  += v[(size_t)s0 * R_ + ch];
    acc2 += v[(size_t)s1 * R_ + ch];
  }
  if (j < j1) acc += v[(size_t)cs[j] * R_ + ch];
  agg[(size_t)node * R_ + ch] = acc + acc2;
}

// ------------- h = relu(x@Ws + agg@Wn + b), M=4096 N=128 K=128x2 -------------
__global__ __launch_bounds__(256) void psi1_gemm(
    const float* __restrict__ xs, const float* __restrict__ aggs,
    const float* __restrict__ xt, const float* __restrict__ aggt,
    const float* __restrict__ Ws, const float* __restrict__ Wn,
    const float* __restrict__ bias, float* __restrict__ hs, float* __restrict__ ht) {
  const float* x   = blockIdx.z ? xt   : xs;
  const float* agg = blockIdx.z ? aggt : aggs;
  float*       h   = blockIdx.z ? ht   : hs;
  int n0 = blockIdx.x * 64, m0 = blockIdx.y * 64;
  int tid = threadIdx.x, tx = tid & 15, ty = tid >> 4;
  __shared__ __align__(16) float sA[16][68];
  __shared__ __align__(16) float sB[16][68];
  float acc[4][4] = {};
  for (int phase = 0; phase < 2; phase++) {
    const float* A  = phase ? agg : x;
    const float* Bw = phase ? Wn  : Ws;
    for (int kb = 0; kb < F_; kb += 16) {
      int row = tid >> 2, k4 = (tid & 3) * 4;
      float4 va = *(const float4*)(A + (size_t)(m0 + row) * F_ + kb + k4);
      sA[k4 + 0][row] = va.x; sA[k4 + 1][row] = va.y;
      sA[k4 + 2][row] = va.z; sA[k4 + 3][row] = va.w;
      int k = tid >> 4, n4 = (tid & 15) * 4;
      *(float4*)&sB[k][n4] = *(const float4*)(Bw + (size_t)(kb + k) * F_ + n0 + n4);
      __syncthreads();
#pragma unroll
      for (int kk = 0; kk < 16; kk++) {
        float a[4], bb[4];
        *(float4*)a  = *(const float4*)&sA[kk][ty * 4];
        *(float4*)bb = *(const float4*)&sB[kk][tx * 4];
#pragma unroll
        for (int i = 0; i < 4; i++)
#pragma unroll
          for (int j = 0; j < 4; j++) acc[i][j] += a[i] * bb[j];
      }
      __syncthreads();
    }
  }
  float4 bv = *(const float4*)(bias + n0 + tx * 4);
  float bj[4] = {bv.x, bv.y, bv.z, bv.w};
#pragma unroll
  for (int i = 0; i < 4; i++) {
    int m = m0 + ty * 4 + i;
    float4 o;
    o.x = fmaxf(acc[i][0] + bj[0], 0.f); o.y = fmaxf(acc[i][1] + bj[1], 0.f);
    o.z = fmaxf(acc[i][2] + bj[2], 0.f); o.w = fmaxf(acc[i][3] + bj[3], 0.f);
    *(float4*)(h + (size_t)m * F_ + n0 + tx * 4) = o;
  }
}

// ---------- S_hat[b] = h_s[b] @ h_t[b]^T  (NT), 128x128 tile, 8x8 micro ----------
__global__ __launch_bounds__(256) void shat_gemm(
    const float* __restrict__ hs, const float* __restrict__ ht, float* __restrict__ S) {
  int b = blockIdx.z;
  int n0 = blockIdx.x * 128, m0 = blockIdx.y * 128;
  int tid = threadIdx.x, tx = tid & 15, ty = tid >> 4;
  __shared__ __align__(16) float sA[16][132];
  __shared__ __align__(16) float sB[16][132];
  float acc[8][8] = {};
  const float* Ag = hs + (size_t)(b * N_ + m0) * F_;
  const float* Bg = ht + (size_t)(b * N_ + n0) * F_;
  for (int kb = 0; kb < F_; kb += 16) {
#pragma unroll
    for (int l = 0; l < 2; l++) {
      int idx = tid + l * 256;
      int row = idx >> 2, k4 = (idx & 3) * 4;
      float4 va = *(const float4*)(Ag + (size_t)row * F_ + kb + k4);
      sA[k4 + 0][row] = va.x; sA[k4 + 1][row] = va.y;
      sA[k4 + 2][row] = va.z; sA[k4 + 3][row] = va.w;
      float4 vb = *(const float4*)(Bg + (size_t)row * F_ + kb + k4);
      sB[k4 + 0][row] = vb.x; sB[k4 + 1][row] = vb.y;
      sB[k4 + 2][row] = vb.z; sB[k4 + 3][row] = vb.w;
    }
    __syncthreads();
#pragma unroll
    for (int kk = 0; kk < 16; kk++) {
      float a[8], bb[8];
      *(float4*)&a[0]  = *(const float4*)&sA[kk][ty * 8];
      *(float4*)&a[4]  = *(const float4*)&sA[kk][ty * 8 + 4];
      *(float4*)&bb[0] = *(const float4*)&sB[kk][tx * 8];
      *(float4*)&bb[4] = *(const float4*)&sB[kk][tx * 8 + 4];
#pragma unroll
      for (int i = 0; i < 8; i++)
#pragma unroll
        for (int j = 0; j < 8; j++) acc[i][j] += a[i] * bb[j];
    }
    __syncthreads();
  }
#pragma unroll
  for (int i = 0; i < 8; i++) {
    size_t off = ((size_t)(b * N_ + m0 + ty * 8 + i)) * N_ + n0 + tx * 8;
    float4 o0 = {acc[i][0], acc[i][1], acc[i][2], acc[i][3]};
    float4 o1 = {acc[i][4], acc[i][5], acc[i][6], acc[i][7]};
    *(float4*)(S + off) = o0; *(float4*)(S + off + 4) = o1;
  }
}

// ---------------- row softmax over N=1024, one block per row ----------------
__global__ __launch_bounds__(256) void softmax_row(
    const float* __restrict__ in, float* __restrict__ out) {
  int row = blockIdx.x;
  float4 v = ((const float4*)(in + (size_t)row * N_))[threadIdx.x];
  float m = fmaxf(fmaxf(v.x, v.y), fmaxf(v.z, v.w));
#pragma unroll
  for (int o = 32; o > 0; o >>= 1) m = fmaxf(m, __shfl_down(m, o, 64));
  __shared__ float rmax[4], rsum[4];
  int wave = threadIdx.x >> 6, lane = threadIdx.x & 63;
  if (lane == 0) rmax[wave] = m;
  __syncthreads();
  m = fmaxf(fmaxf(rmax[0], rmax[1]), fmaxf(rmax[2], rmax[3]));
  float e0 = __expf(v.x - m), e1 = __expf(v.y - m);
  float e2 = __expf(v.z - m), e3 = __expf(v.w - m);
  float s = e0 + e1 + e2 + e3;
#pragma unroll
  for (int o = 32; o > 0; o >>= 1) s += __shfl_down(s, o, 64);
  if (lane == 0) rsum[wave] = s;
  __syncthreads();
  s = rsum[0] + rsum[1] + rsum[2] + rsum[3];
  float inv = 1.f / s;
  float4 o4 = {e0 * inv, e1 * inv, e2 * inv, e3 * inv};
  ((float4*)(out + (size_t)row * N_))[threadIdx.x] = o4;
}

// ------------- r_t[b,t,r] = sum_s S[b,s,t]*r_s[b,s,r]  (atomic over s-chunks) -------------
__global__ __launch_bounds__(256) void rt_gemm(
    const float* __restrict__ S, const float* __restrict__ rs, float* __restrict__ rt) {
  int b = blockIdx.z, s0 = blockIdx.y * 128, t0 = blockIdx.x * 64;
  int tid = threadIdx.x, tl = tid & 63, rg = tid >> 6;
  __shared__ __align__(16) float rsh[128][17];
  for (int i = tid; i < 512; i += 256) {
    int srow = i >> 2, c = (i & 3) * 4;
    float4 v = *(const float4*)(rs + ((size_t)(b * N_ + s0 + srow)) * R_ + c);
    rsh[srow][c] = v.x; rsh[srow][c + 1] = v.y;
    rsh[srow][c + 2] = v.z; rsh[srow][c + 3] = v.w;
  }
  __syncthreads();
  float a0 = 0, a1 = 0, a2 = 0, a3 = 0;
  const float* Sp = S + ((size_t)(b * N_ + s0)) * N_ + t0 + tl;
  int rb = rg * 4;
  for (int s = 0; s < 128; s++) {
    float sv = Sp[(size_t)s * N_];
    a0 += sv * rsh[s][rb + 0]; a1 += sv * rsh[s][rb + 1];
    a2 += sv * rsh[s][rb + 2]; a3 += sv * rsh[s][rb + 3];
  }
  float* o = rt + ((size_t)(b * N_ + t0 + tl)) * R_ + rb;
  atomicAdd(o + 0, a0); atomicAdd(o + 1, a1);
  atomicAdd(o + 2, a2); atomicAdd(o + 3, a3);
}

// ------- P = relu(v@W2s + agg@W2n + b2) @ Wm1, rows of 16, R=16 -------
__global__ __launch_bounds__(256) void psi2p(
    const float* __restrict__ vs, const float* __restrict__ aggs_,
    const float* __restrict__ vt, const float* __restrict__ aggt_,
    const float* __restrict__ W2s, const float* __restrict__ W2n,
    const float* __restrict__ b2, const float* __restrict__ Wm1,
    float* __restrict__ Ps, float* __restrict__ Pt) {
  const float* v   = blockIdx.y ? vt    : vs;
  const float* agg = blockIdx.y ? aggt_ : aggs_;
  float*       P   = blockIdx.y ? Pt    : Ps;
  int col = threadIdx.x & 15, row = threadIdx.x >> 4;
  int r0 = blockIdx.x * 16;
  __shared__ float sWs[16][16], sWn[16][16], sWm[16][17];
  __shared__ float sv[16][17], sa[16][17], so[16][17];
  sWs[row][col] = W2s[row * 16 + col];
  sWn[row][col] = W2n[row * 16 + col];
  sWm[row][col] = Wm1[row * 16 + col];
  sv[row][col] = v[(size_t)(r0 + row) * R_ + col];
  sa[row][col] = agg[(size_t)(r0 + row) * R_ + col];
  __syncthreads();
  float o = b2[col];
#pragma unroll
  for (int k = 0; k < 16; k++) o += sv[row][k] * sWs[k][col] + sa[row][k] * sWn[k][col];
  so[row][col] = fmaxf(o, 0.f);
  __syncthreads();
  float p = 0;
#pragma unroll
  for (int k = 0; k < 16; k++) p += so[row][k] * sWm[k][col];
  P[(size_t)(r0 + row) * R_ + col] = p;
}

// ---- S_hat[b,s,t] += sum_r relu(Ps[b,s,r]-Pt[b,t,r]+bm1[r])*Wm2[r] + bm2 ----
__global__ __launch_bounds__(256) void upd_kernel(
    float* __restrict__ Shat, const float* __restrict__ Ps, const float* __restrict__ Pt,
    const float* __restrict__ bm1, const float* __restrict__ Wm2,
    const float* __restrict__ bm2) {
  int b = blockIdx.z, s0 = blockIdx.y * 4, t0 = blockIdx.x * 256;
  int tid = threadIdx.x;
  __shared__ float pt[256][17];
  __shared__ float ps[4][16];
  __shared__ float sb[16], sw[16];
  for (int i = tid; i < 1024; i += 256) {
    int tr = i >> 2, c = (i & 3) * 4;
    const float4 v = *(const float4*)(Pt + ((size_t)(b * N_ + t0 + tr)) * R_ + c);
    pt[tr][c] = v.x; pt[tr][c + 1] = v.y; pt[tr][c + 2] = v.z; pt[tr][c + 3] = v.w;
  }
  if (tid < 64) ps[tid >> 4][tid & 15] = Ps[((size_t)(b * N_ + s0 + (tid >> 4))) * R_ + (tid & 15)];
  if (tid < 16) { sb[tid] = bm1[tid]; sw[tid] = Wm2[tid]; }
  __syncthreads();
  float bm2v = bm2[0];
  float ptl[16];
#pragma unroll
  for (int r = 0; r < 16; r++) ptl[r] = pt[tid][r];
#pragma unroll
  for (int si = 0; si < 4; si++) {
    size_t off = ((size_t)(b * N_ + s0 + si)) * N_ + t0 + tid;
    float sum = bm2v;
#pragma unroll
    for (int r = 0; r < 16; r++) sum += fmaxf(ps[si][r] - ptl[r] + sb[r], 0.f) * sw[r];
    Shat[off] += sum;
  }
}

extern "C" void kernel_launch(void* const* d_in, const int* in_sizes, int n_in,
                              void* d_out, int out_size, void* d_ws, size_t ws_size,
                              hipStream_t stream) {
  const float* x_s = (const float*)d_in[0];
  const int*   ei_s = (const int*)d_in[1];
  const float* x_t = (const float*)d_in[2];
  const int*   ei_t = (const int*)d_in[3];
  const float* W1s = (const float*)d_in[4];
  const float* W1n = (const float*)d_in[5];
  const float* b1  = (const float*)d_in[6];
  const float* W2s = (const float*)d_in[7];
  const float* W2n = (const float*)d_in[8];
  const float* b2  = (const float*)d_in[9];
  const float* Wm1 = (const float*)d_in[10];
  const float* bm1 = (const float*)d_in[11];
  const float* Wm2 = (const float*)d_in[12];
  const float* bm2 = (const float*)d_in[13];
  const float* r_steps = (const float*)d_in[14];

  float* out = (float*)d_out;
  float* S0 = out;                         // [4,1024,1024]
  float* SL = out + (size_t)B_ * N_ * N_;  // [4,1024,1024] (also scratch for step-1 S)

  float* ws = (float*)d_ws;
  float* agg_s = ws;                       // 524288
  float* agg_t = ws + 524288;              // 524288
  float* h_s   = ws + 1048576;             // 524288
  float* h_t   = ws + 1572864;             // 524288
  float* Shat  = ws + 2097152;             // 4194304
  float* rtb   = ws + 6291456;             // 65536
  float* agg2s = ws + 6356992;             // 65536
  float* agg2t = ws + 6422528;             // 65536
  float* Ps    = ws + 6488064;             // 65536
  float* Pt    = ws + 6553600;             // 65536
  int* counts  = (int*)(ws + 6619136);     // 8192
  int* cursor  = (int*)(ws + 6627328);     // 8192
  int* offs    = (int*)(ws + 6635520);     // 8194 (2 x 4097)
  int* csr     = (int*)(ws + 6643720);     // 131072

  // ---- CSR build (per call; edges are inputs, ws is re-poisoned) ----
  hipMemsetAsync(counts, 0, 2 * BN_ * sizeof(int), stream);
  hist_k<<<dim3(E_ / 256, 2), 256, 0, stream>>>(ei_s, ei_t, counts);
  csr_scan<<<2, 256, 0, stream>>>(counts, offs, cursor);
  csr_fill<<<dim3(E_ / 256, 2), 256, 0, stream>>>(ei_s, ei_t, cursor, csr);

  // ---- psi1 on both graphs (gather, no atomics) ----
  gather_f<<<dim3(BN_ / 2, 2), 256, 0, stream>>>(x_s, x_t, csr, offs, agg_s, agg_t);
  psi1_gemm<<<dim3(2, 64, 2), 256, 0, stream>>>(x_s, agg_s, x_t, agg_t, W1s, W1n, b1, h_s, h_t);

  // ---- S_hat and S_0 ----
  shat_gemm<<<dim3(8, 8, 4), 256, 0, stream>>>(h_s, h_t, Shat);
  softmax_row<<<B_ * N_, 256, 0, stream>>>(Shat, S0);

  for (int step = 0; step < 2; step++) {
    const float* rs = r_steps + (size_t)step * B_ * N_ * R_;
    const float* Scur;
    if (step == 0) {
      Scur = S0;  // softmax(S_hat) at step 0 is exactly S_0
    } else {
      softmax_row<<<B_ * N_, 256, 0, stream>>>(Shat, SL);  // SL region as scratch
      Scur = SL;
    }
    hipMemsetAsync(rtb, 0, 65536 * sizeof(float), stream);
    rt_gemm<<<dim3(16, 8, 4), 256, 0, stream>>>(Scur, rs, rtb);
    gather_r<<<dim3(BN_ / 16, 2), 256, 0, stream>>>(rs, rtb, csr, offs, agg2s, agg2t);
    psi2p<<<dim3(256, 2), 256, 0, stream>>>(rs, agg2s, rtb, agg2t, W2s, W2n, b2, Wm1, Ps, Pt);
    upd_kernel<<<dim3(4, 256, 4), 256, 0, stream>>>(Shat, Ps, Pt, bm1, Wm2, bm2);
  }

  // ---- final S_L ----
  softmax_row<<<B_ * N_, 256, 0, stream>>>(Shat, SL);
}

// Round 3
// 268.693 us; speedup vs baseline: 2.1396x; 1.2505x over previous
//
#include <hip/hip_runtime.h>

#define B_ 4
#define N_ 1024
#define F_ 128
#define R_ 16
#define E_ 65536
#define BN_ 4096

// ---------------- CSR build: histogram of dst ----------------
__global__ __launch_bounds__(256) void hist_k(
    const int* __restrict__ eis, const int* __restrict__ eit, int* __restrict__ counts) {
  const int* ei = blockIdx.y ? eit : eis;
  int* c = counts + blockIdx.y * BN_;
  int e = blockIdx.x * 256 + threadIdx.x;
  atomicAdd(c + ei[E_ + e], 1);
}

// ---------------- CSR build: exclusive scan (4096 = 256 threads x 16) ----------------
__global__ __launch_bounds__(256) void csr_scan(
    const int* __restrict__ counts, int* __restrict__ offs, int* __restrict__ cursor) {
  const int* c = counts + blockIdx.x * BN_;
  int* o = offs + blockIdx.x * (BN_ + 1);
  int* cur = cursor + blockIdx.x * BN_;
  int tid = threadIdx.x;
  int base = tid * 16;
  int local[16], sum = 0;
#pragma unroll
  for (int i = 0; i < 16; i++) { local[i] = sum; sum += c[base + i]; }
  __shared__ int csum[256];
  csum[tid] = sum;
  __syncthreads();
  for (int d = 1; d < 256; d <<= 1) {
    int v = (tid >= d) ? csum[tid - d] : 0;
    __syncthreads();
    csum[tid] += v;
    __syncthreads();
  }
  int prev = (tid == 0) ? 0 : csum[tid - 1];
#pragma unroll
  for (int i = 0; i < 16; i++) { int off = prev + local[i]; o[base + i] = off; cur[base + i] = off; }
  if (tid == 255) o[BN_] = csum[255];
}

// ---------------- CSR build: fill src lists ----------------
__global__ __launch_bounds__(256) void csr_fill(
    const int* __restrict__ eis, const int* __restrict__ eit,
    int* __restrict__ cursor, int* __restrict__ csr) {
  const int* ei = blockIdx.y ? eit : eis;
  int* cur = cursor + blockIdx.y * BN_;
  int* cs = csr + blockIdx.y * E_;
  int e = blockIdx.x * 256 + threadIdx.x;
  int src = ei[e], dst = ei[E_ + e];
  int pos = atomicAdd(cur + dst, 1);
  cs[pos] = src;
}

// ---------------- psi1 aggregation via gather: agg[n] = sum_{src in csr[n]} x[src] ----------------
__global__ __launch_bounds__(256) void gather_f(
    const float* __restrict__ xs, const float* __restrict__ xt,
    const int* __restrict__ csr, const int* __restrict__ offs,
    float* __restrict__ aggs, float* __restrict__ aggt) {
  const float* x = blockIdx.y ? xt : xs;
  const int* cs = csr + blockIdx.y * E_;
  const int* of = offs + blockIdx.y * (BN_ + 1);
  float* agg = blockIdx.y ? aggt : aggs;
  int node = blockIdx.x * 2 + (threadIdx.x >> 7);
  int ch = threadIdx.x & 127;
  int j0 = of[node], j1 = of[node + 1];
  float acc = 0.f, acc2 = 0.f;
  int j = j0;
  for (; j + 1 < j1; j += 2) {
    int s0 = cs[j], s1 = cs[j + 1];
    acc  += x[(size_t)s0 * F_ + ch];
    acc2 += x[(size_t)s1 * F_ + ch];
  }
  if (j < j1) acc += x[(size_t)cs[j] * F_ + ch];
  agg[(size_t)node * F_ + ch] = acc + acc2;
}

// ---------------- psi2 aggregation via gather, R=16 ----------------
__global__ __launch_bounds__(256) void gather_r(
    const float* __restrict__ rs, const float* __restrict__ rtv,
    const int* __restrict__ csr, const int* __restrict__ offs,
    float* __restrict__ aggs, float* __restrict__ aggt) {
  const float* v = blockIdx.y ? rtv : rs;
  const int* cs = csr + blockIdx.y * E_;
  const int* of = offs + blockIdx.y * (BN_ + 1);
  float* agg = blockIdx.y ? aggt : aggs;
  int node = blockIdx.x * 16 + (threadIdx.x >> 4);
  int ch = threadIdx.x & 15;
  int j0 = of[node], j1 = of[node + 1];
  float acc = 0.f, acc2 = 0.f;
  int j = j0;
  for (; j + 1 < j1; j += 2) {
    int s0 = cs[j], s1 = cs[j + 1];
    acc  += v[(size_t)s0 * R_ + ch];
    acc2 += v[(size_t)s1 * R_ + ch];
  }
  if (j < j1) acc += v[(size_t)cs[j] * R_ + ch];
  agg[(size_t)node * R_ + ch] = acc + acc2;
}

// ------------- h = relu(x@Ws + agg@Wn + b), M=4096 N=128 K=128x2 -------------
__global__ __launch_bounds__(256) void psi1_gemm(
    const float* __restrict__ xs, const float* __restrict__ aggs,
    const float* __restrict__ xt, const float* __restrict__ aggt,
    const float* __restrict__ Ws, const float* __restrict__ Wn,
    const float* __restrict__ bias, float* __restrict__ hs, float* __restrict__ ht) {
  const float* x   = blockIdx.z ? xt   : xs;
  const float* agg = blockIdx.z ? aggt : aggs;
  float*       h   = blockIdx.z ? ht   : hs;
  int n0 = blockIdx.x * 64, m0 = blockIdx.y * 64;
  int tid = threadIdx.x, tx = tid & 15, ty = tid >> 4;
  __shared__ __align__(16) float sA[16][68];
  __shared__ __align__(16) float sB[16][68];
  float acc[4][4] = {};
  for (int phase = 0; phase < 2; phase++) {
    const float* A  = phase ? agg : x;
    const float* Bw = phase ? Wn  : Ws;
    for (int kb = 0; kb < F_; kb += 16) {
      int row = tid >> 2, k4 = (tid & 3) * 4;
      float4 va = *(const float4*)(A + (size_t)(m0 + row) * F_ + kb + k4);
      sA[k4 + 0][row] = va.x; sA[k4 + 1][row] = va.y;
      sA[k4 + 2][row] = va.z; sA[k4 + 3][row] = va.w;
      int k = tid >> 4, n4 = (tid & 15) * 4;
      *(float4*)&sB[k][n4] = *(const float4*)(Bw + (size_t)(kb + k) * F_ + n0 + n4);
      __syncthreads();
#pragma unroll
      for (int kk = 0; kk < 16; kk++) {
        float a[4], bb[4];
        *(float4*)a  = *(const float4*)&sA[kk][ty * 4];
        *(float4*)bb = *(const float4*)&sB[kk][tx * 4];
#pragma unroll
        for (int i = 0; i < 4; i++)
#pragma unroll
          for (int j = 0; j < 4; j++) acc[i][j] += a[i] * bb[j];
      }
      __syncthreads();
    }
  }
  float4 bv = *(const float4*)(bias + n0 + tx * 4);
  float bj[4] = {bv.x, bv.y, bv.z, bv.w};
#pragma unroll
  for (int i = 0; i < 4; i++) {
    int m = m0 + ty * 4 + i;
    float4 o;
    o.x = fmaxf(acc[i][0] + bj[0], 0.f); o.y = fmaxf(acc[i][1] + bj[1], 0.f);
    o.z = fmaxf(acc[i][2] + bj[2], 0.f); o.w = fmaxf(acc[i][3] + bj[3], 0.f);
    *(float4*)(h + (size_t)m * F_ + n0 + tx * 4) = o;
  }
}

// ---------- S_hat[b] = h_s[b] @ h_t[b]^T  (NT), 128x128 tile, 8x8 micro ----------
__global__ __launch_bounds__(256) void shat_gemm(
    const float* __restrict__ hs, const float* __restrict__ ht, float* __restrict__ S) {
  int b = blockIdx.z;
  int n0 = blockIdx.x * 128, m0 = blockIdx.y * 128;
  int tid = threadIdx.x, tx = tid & 15, ty = tid >> 4;
  __shared__ __align__(16) float sA[16][132];
  __shared__ __align__(16) float sB[16][132];
  float acc[8][8] = {};
  const float* Ag = hs + (size_t)(b * N_ + m0) * F_;
  const float* Bg = ht + (size_t)(b * N_ + n0) * F_;
  for (int kb = 0; kb < F_; kb += 16) {
#pragma unroll
    for (int l = 0; l < 2; l++) {
      int idx = tid + l * 256;
      int row = idx >> 2, k4 = (idx & 3) * 4;
      float4 va = *(const float4*)(Ag + (size_t)row * F_ + kb + k4);
      sA[k4 + 0][row] = va.x; sA[k4 + 1][row] = va.y;
      sA[k4 + 2][row] = va.z; sA[k4 + 3][row] = va.w;
      float4 vb = *(const float4*)(Bg + (size_t)row * F_ + kb + k4);
      sB[k4 + 0][row] = vb.x; sB[k4 + 1][row] = vb.y;
      sB[k4 + 2][row] = vb.z; sB[k4 + 3][row] = vb.w;
    }
    __syncthreads();
#pragma unroll
    for (int kk = 0; kk < 16; kk++) {
      float a[8], bb[8];
      *(float4*)&a[0]  = *(const float4*)&sA[kk][ty * 8];
      *(float4*)&a[4]  = *(const float4*)&sA[kk][ty * 8 + 4];
      *(float4*)&bb[0] = *(const float4*)&sB[kk][tx * 8];
      *(float4*)&bb[4] = *(const float4*)&sB[kk][tx * 8 + 4];
#pragma unroll
      for (int i = 0; i < 8; i++)
#pragma unroll
        for (int j = 0; j < 8; j++) acc[i][j] += a[i] * bb[j];
    }
    __syncthreads();
  }
#pragma unroll
  for (int i = 0; i < 8; i++) {
    size_t off = ((size_t)(b * N_ + m0 + ty * 8 + i)) * N_ + n0 + tx * 8;
    float4 o0 = {acc[i][0], acc[i][1], acc[i][2], acc[i][3]};
    float4 o1 = {acc[i][4], acc[i][5], acc[i][6], acc[i][7]};
    *(float4*)(S + off) = o0; *(float4*)(S + off + 4) = o1;
  }
}

// ---------------- row softmax over N=1024, one block per row ----------------
__global__ __launch_bounds__(256) void softmax_row(
    const float* __restrict__ in, float* __restrict__ out) {
  int row = blockIdx.x;
  float4 v = ((const float4*)(in + (size_t)row * N_))[threadIdx.x];
  float m = fmaxf(fmaxf(v.x, v.y), fmaxf(v.z, v.w));
#pragma unroll
  for (int o = 32; o > 0; o >>= 1) m = fmaxf(m, __shfl_down(m, o, 64));
  __shared__ float rmax[4], rsum[4];
  int wave = threadIdx.x >> 6, lane = threadIdx.x & 63;
  if (lane == 0) rmax[wave] = m;
  __syncthreads();
  m = fmaxf(fmaxf(rmax[0], rmax[1]), fmaxf(rmax[2], rmax[3]));
  float e0 = __expf(v.x - m), e1 = __expf(v.y - m);
  float e2 = __expf(v.z - m), e3 = __expf(v.w - m);
  float s = e0 + e1 + e2 + e3;
#pragma unroll
  for (int o = 32; o > 0; o >>= 1) s += __shfl_down(s, o, 64);
  if (lane == 0) rsum[wave] = s;
  __syncthreads();
  s = rsum[0] + rsum[1] + rsum[2] + rsum[3];
  float inv = 1.f / s;
  float4 o4 = {e0 * inv, e1 * inv, e2 * inv, e3 * inv};
  ((float4*)(out + (size_t)row * N_))[threadIdx.x] = o4;
}

// ---- r_t partial: part[b][c][t][r] = sum_{s in chunk c} S[b,s,t]*r_s[b,s,r] ----
// block = 256 t (1 per thread), 16 r accumulators in VGPRs, s-chunk = 32 (unrolled)
__global__ __launch_bounds__(256) void rt_part(
    const float* __restrict__ S, const float* __restrict__ rs, float* __restrict__ part) {
  int b = blockIdx.z, c = blockIdx.y, t0 = blockIdx.x * 256;
  int tid = threadIdx.x;
  int s0 = c * 32;
  __shared__ float rsh[32][16];
  if (tid < 128) {
    int srow = tid >> 2, c4 = (tid & 3) * 4;
    float4 v = *(const float4*)(rs + ((size_t)(b * N_ + s0 + srow)) * R_ + c4);
    rsh[srow][c4] = v.x; rsh[srow][c4 + 1] = v.y;
    rsh[srow][c4 + 2] = v.z; rsh[srow][c4 + 3] = v.w;
  }
  __syncthreads();
  float acc[16] = {};
  const float* Sp = S + ((size_t)(b * N_ + s0)) * N_ + t0 + tid;
#pragma unroll
  for (int s = 0; s < 32; s++) {
    float sv = Sp[(size_t)s * N_];
#pragma unroll
    for (int r = 0; r < 16; r++) acc[r] += sv * rsh[s][r];
  }
  float* o = part + ((size_t)((b * 32 + c) * N_) + t0 + tid) * R_;
  *(float4*)(o + 0)  = *(float4*)&acc[0];
  *(float4*)(o + 4)  = *(float4*)&acc[4];
  *(float4*)(o + 8)  = *(float4*)&acc[8];
  *(float4*)(o + 12) = *(float4*)&acc[12];
}

// ---- r_t reduce over 32 chunks: rt[b][t][r] = sum_c part[b][c][t][r] ----
__global__ __launch_bounds__(256) void rt_reduce(
    const float* __restrict__ part, float* __restrict__ rt) {
  int gid = blockIdx.x * 256 + threadIdx.x;   // 16384 float4 outputs
  int b = gid >> 12, tr = gid & 4095;
  const float* p = part + (size_t)b * (32 * N_ * R_) + (size_t)tr * 4;
  float4 acc = {0.f, 0.f, 0.f, 0.f};
#pragma unroll
  for (int c = 0; c < 32; c++) {
    float4 v = *(const float4*)(p + (size_t)c * (N_ * R_));
    acc.x += v.x; acc.y += v.y; acc.z += v.z; acc.w += v.w;
  }
  ((float4*)rt)[gid] = acc;
}

// ------- P = relu(v@W2s + agg@W2n + b2) @ Wm1, rows of 16, R=16 -------
__global__ __launch_bounds__(256) void psi2p(
    const float* __restrict__ vs, const float* __restrict__ aggs_,
    const float* __restrict__ vt, const float* __restrict__ aggt_,
    const float* __restrict__ W2s, const float* __restrict__ W2n,
    const float* __restrict__ b2, const float* __restrict__ Wm1,
    float* __restrict__ Ps, float* __restrict__ Pt) {
  const float* v   = blockIdx.y ? vt    : vs;
  const float* agg = blockIdx.y ? aggt_ : aggs_;
  float*       P   = blockIdx.y ? Pt    : Ps;
  int col = threadIdx.x & 15, row = threadIdx.x >> 4;
  int r0 = blockIdx.x * 16;
  __shared__ float sWs[16][16], sWn[16][16], sWm[16][17];
  __shared__ float sv[16][17], sa[16][17], so[16][17];
  sWs[row][col] = W2s[row * 16 + col];
  sWn[row][col] = W2n[row * 16 + col];
  sWm[row][col] = Wm1[row * 16 + col];
  sv[row][col] = v[(size_t)(r0 + row) * R_ + col];
  sa[row][col] = agg[(size_t)(r0 + row) * R_ + col];
  __syncthreads();
  float o = b2[col];
#pragma unroll
  for (int k = 0; k < 16; k++) o += sv[row][k] * sWs[k][col] + sa[row][k] * sWn[k][col];
  so[row][col] = fmaxf(o, 0.f);
  __syncthreads();
  float p = 0;
#pragma unroll
  for (int k = 0; k < 16; k++) p += so[row][k] * sWm[k][col];
  P[(size_t)(r0 + row) * R_ + col] = p;
}

// ---- S_hat[b,s,t] += sum_r relu(Ps[b,s,r]-Pt[b,t,r]+bm1[r])*Wm2[r] + bm2 ----
__global__ __launch_bounds__(256) void upd_kernel(
    float* __restrict__ Shat, const float* __restrict__ Ps, const float* __restrict__ Pt,
    const float* __restrict__ bm1, const float* __restrict__ Wm2,
    const float* __restrict__ bm2) {
  int b = blockIdx.z, s0 = blockIdx.y * 4, t0 = blockIdx.x * 256;
  int tid = threadIdx.x;
  __shared__ float pt[256][17];
  __shared__ float ps[4][16];
  __shared__ float sb[16], sw[16];
  for (int i = tid; i < 1024; i += 256) {
    int tr = i >> 2, c = (i & 3) * 4;
    const float4 v = *(const float4*)(Pt + ((size_t)(b * N_ + t0 + tr)) * R_ + c);
    pt[tr][c] = v.x; pt[tr][c + 1] = v.y; pt[tr][c + 2] = v.z; pt[tr][c + 3] = v.w;
  }
  if (tid < 64) ps[tid >> 4][tid & 15] = Ps[((size_t)(b * N_ + s0 + (tid >> 4))) * R_ + (tid & 15)];
  if (tid < 16) { sb[tid] = bm1[tid]; sw[tid] = Wm2[tid]; }
  __syncthreads();
  float bm2v = bm2[0];
  float ptl[16];
#pragma unroll
  for (int r = 0; r < 16; r++) ptl[r] = pt[tid][r];
#pragma unroll
  for (int si = 0; si < 4; si++) {
    size_t off = ((size_t)(b * N_ + s0 + si)) * N_ + t0 + tid;
    float sum = bm2v;
#pragma unroll
    for (int r = 0; r < 16; r++) sum += fmaxf(ps[si][r] - ptl[r] + sb[r], 0.f) * sw[r];
    Shat[off] += sum;
  }
}

extern "C" void kernel_launch(void* const* d_in, const int* in_sizes, int n_in,
                              void* d_out, int out_size, void* d_ws, size_t ws_size,
                              hipStream_t stream) {
  const float* x_s = (const float*)d_in[0];
  const int*   ei_s = (const int*)d_in[1];
  const float* x_t = (const float*)d_in[2];
  const int*   ei_t = (const int*)d_in[3];
  const float* W1s = (const float*)d_in[4];
  const float* W1n = (const float*)d_in[5];
  const float* b1  = (const float*)d_in[6];
  const float* W2s = (const float*)d_in[7];
  const float* W2n = (const float*)d_in[8];
  const float* b2  = (const float*)d_in[9];
  const float* Wm1 = (const float*)d_in[10];
  const float* bm1 = (const float*)d_in[11];
  const float* Wm2 = (const float*)d_in[12];
  const float* bm2 = (const float*)d_in[13];
  const float* r_steps = (const float*)d_in[14];

  float* out = (float*)d_out;
  float* S0 = out;                         // [4,1024,1024]
  float* SL = out + (size_t)B_ * N_ * N_;  // [4,1024,1024] (also scratch for step-1 S)

  float* ws = (float*)d_ws;
  float* agg_s = ws;                       // 524288   (dead after psi1_gemm)
  float* agg_t = ws + 524288;              // 524288   (dead after psi1_gemm)
  float* h_s   = ws + 1048576;             // 524288   (dead after shat_gemm)
  float* h_t   = ws + 1572864;             // 524288   (dead after shat_gemm)
  float* part  = ws;                       // 2097152 floats = 8MB, reuses agg+h region
  float* Shat  = ws + 2097152;             // 4194304
  float* rtb   = ws + 6291456;             // 65536
  float* agg2s = ws + 6356992;             // 65536
  float* agg2t = ws + 6422528;             // 65536
  float* Ps    = ws + 6488064;             // 65536
  float* Pt    = ws + 6553600;             // 65536
  int* counts  = (int*)(ws + 6619136);     // 8192
  int* cursor  = (int*)(ws + 6627328);     // 8192
  int* offs    = (int*)(ws + 6635520);     // 8194 (2 x 4097)
  int* csr     = (int*)(ws + 6643720);     // 131072

  // ---- CSR build ----
  hipMemsetAsync(counts, 0, 2 * BN_ * sizeof(int), stream);
  hist_k<<<dim3(E_ / 256, 2), 256, 0, stream>>>(ei_s, ei_t, counts);
  csr_scan<<<2, 256, 0, stream>>>(counts, offs, cursor);
  csr_fill<<<dim3(E_ / 256, 2), 256, 0, stream>>>(ei_s, ei_t, cursor, csr);

  // ---- psi1 on both graphs (gather, no atomics) ----
  gather_f<<<dim3(BN_ / 2, 2), 256, 0, stream>>>(x_s, x_t, csr, offs, agg_s, agg_t);
  psi1_gemm<<<dim3(2, 64, 2), 256, 0, stream>>>(x_s, agg_s, x_t, agg_t, W1s, W1n, b1, h_s, h_t);

  // ---- S_hat and S_0 ----
  shat_gemm<<<dim3(8, 8, 4), 256, 0, stream>>>(h_s, h_t, Shat);
  softmax_row<<<B_ * N_, 256, 0, stream>>>(Shat, S0);

  for (int step = 0; step < 2; step++) {
    const float* rs = r_steps + (size_t)step * B_ * N_ * R_;
    const float* Scur;
    if (step == 0) {
      Scur = S0;  // softmax(S_hat) at step 0 is exactly S_0
    } else {
      softmax_row<<<B_ * N_, 256, 0, stream>>>(Shat, SL);  // SL region as scratch
      Scur = SL;
    }
    rt_part<<<dim3(4, 32, 4), 256, 0, stream>>>(Scur, rs, part);
    rt_reduce<<<64, 256, 0, stream>>>(part, rtb);
    gather_r<<<dim3(BN_ / 16, 2), 256, 0, stream>>>(rs, rtb, csr, offs, agg2s, agg2t);
    psi2p<<<dim3(256, 2), 256, 0, stream>>>(rs, agg2s, rtb, agg2t, W2s, W2n, b2, Wm1, Ps, Pt);
    upd_kernel<<<dim3(4, 256, 4), 256, 0, stream>>>(Shat, Ps, Pt, bm1, Wm2, bm2);
  }

  // ---- final S_L ----
  softmax_row<<<B_ * N_, 256, 0, stream>>>(Shat, SL);
}

// Round 4
// 257.031 us; speedup vs baseline: 2.2367x; 1.0454x over previous
//
#include <hip/hip_runtime.h>

#define B_ 4
#define N_ 1024
#define F_ 128
#define R_ 16
#define E_ 65536
#define BN_ 4096

// ---------------- CSR build: histogram of dst ----------------
__global__ __launch_bounds__(256) void hist_k(
    const int* __restrict__ eis, const int* __restrict__ eit, int* __restrict__ counts) {
  const int* ei = blockIdx.y ? eit : eis;
  int* c = counts + blockIdx.y * BN_;
  int e = blockIdx.x * 256 + threadIdx.x;
  atomicAdd(c + ei[E_ + e], 1);
}

// ---------------- CSR build: exclusive scan (4096 = 256 threads x 16) ----------------
__global__ __launch_bounds__(256) void csr_scan(
    const int* __restrict__ counts, int* __restrict__ offs, int* __restrict__ cursor) {
  const int* c = counts + blockIdx.x * BN_;
  int* o = offs + blockIdx.x * (BN_ + 1);
  int* cur = cursor + blockIdx.x * BN_;
  int tid = threadIdx.x;
  int base = tid * 16;
  int local[16], sum = 0;
#pragma unroll
  for (int i = 0; i < 16; i++) { local[i] = sum; sum += c[base + i]; }
  __shared__ int csum[256];
  csum[tid] = sum;
  __syncthreads();
  for (int d = 1; d < 256; d <<= 1) {
    int v = (tid >= d) ? csum[tid - d] : 0;
    __syncthreads();
    csum[tid] += v;
    __syncthreads();
  }
  int prev = (tid == 0) ? 0 : csum[tid - 1];
#pragma unroll
  for (int i = 0; i < 16; i++) { int off = prev + local[i]; o[base + i] = off; cur[base + i] = off; }
  if (tid == 255) o[BN_] = csum[255];
}

// ---------------- CSR build: fill src lists ----------------
__global__ __launch_bounds__(256) void csr_fill(
    const int* __restrict__ eis, const int* __restrict__ eit,
    int* __restrict__ cursor, int* __restrict__ csr) {
  const int* ei = blockIdx.y ? eit : eis;
  int* cur = cursor + blockIdx.y * BN_;
  int* cs = csr + blockIdx.y * E_;
  int e = blockIdx.x * 256 + threadIdx.x;
  int src = ei[e], dst = ei[E_ + e];
  int pos = atomicAdd(cur + dst, 1);
  cs[pos] = src;
}

// ---------------- psi1 aggregation via gather, 4-way ILP ----------------
__global__ __launch_bounds__(256) void gather_f(
    const float* __restrict__ xs, const float* __restrict__ xt,
    const int* __restrict__ csr, const int* __restrict__ offs,
    float* __restrict__ aggs, float* __restrict__ aggt) {
  const float* x = blockIdx.y ? xt : xs;
  const int* cs = csr + blockIdx.y * E_;
  const int* of = offs + blockIdx.y * (BN_ + 1);
  float* agg = blockIdx.y ? aggt : aggs;
  int node = blockIdx.x * 2 + (threadIdx.x >> 7);
  int ch = threadIdx.x & 127;
  int j0 = of[node], j1 = of[node + 1];
  float a0 = 0.f, a1 = 0.f, a2 = 0.f, a3 = 0.f;
  int j = j0;
  for (; j + 3 < j1; j += 4) {
    int s0 = cs[j], s1 = cs[j + 1], s2 = cs[j + 2], s3 = cs[j + 3];
    a0 += x[(size_t)s0 * F_ + ch];
    a1 += x[(size_t)s1 * F_ + ch];
    a2 += x[(size_t)s2 * F_ + ch];
    a3 += x[(size_t)s3 * F_ + ch];
  }
  for (; j < j1; j++) a0 += x[(size_t)cs[j] * F_ + ch];
  agg[(size_t)node * F_ + ch] = (a0 + a1) + (a2 + a3);
}

// ------------- h = relu(x@Ws + agg@Wn + b), M=4096 N=128 K=128x2 -------------
__global__ __launch_bounds__(256) void psi1_gemm(
    const float* __restrict__ xs, const float* __restrict__ aggs,
    const float* __restrict__ xt, const float* __restrict__ aggt,
    const float* __restrict__ Ws, const float* __restrict__ Wn,
    const float* __restrict__ bias, float* __restrict__ hs, float* __restrict__ ht) {
  const float* x   = blockIdx.z ? xt   : xs;
  const float* agg = blockIdx.z ? aggt : aggs;
  float*       h   = blockIdx.z ? ht   : hs;
  int n0 = blockIdx.x * 64, m0 = blockIdx.y * 64;
  int tid = threadIdx.x, tx = tid & 15, ty = tid >> 4;
  __shared__ __align__(16) float sA[16][68];
  __shared__ __align__(16) float sB[16][68];
  float acc[4][4] = {};
  for (int phase = 0; phase < 2; phase++) {
    const float* A  = phase ? agg : x;
    const float* Bw = phase ? Wn  : Ws;
    for (int kb = 0; kb < F_; kb += 16) {
      int row = tid >> 2, k4 = (tid & 3) * 4;
      float4 va = *(const float4*)(A + (size_t)(m0 + row) * F_ + kb + k4);
      sA[k4 + 0][row] = va.x; sA[k4 + 1][row] = va.y;
      sA[k4 + 2][row] = va.z; sA[k4 + 3][row] = va.w;
      int k = tid >> 4, n4 = (tid & 15) * 4;
      *(float4*)&sB[k][n4] = *(const float4*)(Bw + (size_t)(kb + k) * F_ + n0 + n4);
      __syncthreads();
#pragma unroll
      for (int kk = 0; kk < 16; kk++) {
        float a[4], bb[4];
        *(float4*)a  = *(const float4*)&sA[kk][ty * 4];
        *(float4*)bb = *(const float4*)&sB[kk][tx * 4];
#pragma unroll
        for (int i = 0; i < 4; i++)
#pragma unroll
          for (int j = 0; j < 4; j++) acc[i][j] += a[i] * bb[j];
      }
      __syncthreads();
    }
  }
  float4 bv = *(const float4*)(bias + n0 + tx * 4);
  float bj[4] = {bv.x, bv.y, bv.z, bv.w};
#pragma unroll
  for (int i = 0; i < 4; i++) {
    int m = m0 + ty * 4 + i;
    float4 o;
    o.x = fmaxf(acc[i][0] + bj[0], 0.f); o.y = fmaxf(acc[i][1] + bj[1], 0.f);
    o.z = fmaxf(acc[i][2] + bj[2], 0.f); o.w = fmaxf(acc[i][3] + bj[3], 0.f);
    *(float4*)(h + (size_t)m * F_ + n0 + tx * 4) = o;
  }
}

// ---------- S_hat[b] = h_s[b] @ h_t[b]^T  (NT), 128x128 tile, 8x8 micro ----------
__global__ __launch_bounds__(256) void shat_gemm(
    const float* __restrict__ hs, const float* __restrict__ ht, float* __restrict__ S) {
  int b = blockIdx.z;
  int n0 = blockIdx.x * 128, m0 = blockIdx.y * 128;
  int tid = threadIdx.x, tx = tid & 15, ty = tid >> 4;
  __shared__ __align__(16) float sA[16][132];
  __shared__ __align__(16) float sB[16][132];
  float acc[8][8] = {};
  const float* Ag = hs + (size_t)(b * N_ + m0) * F_;
  const float* Bg = ht + (size_t)(b * N_ + n0) * F_;
  for (int kb = 0; kb < F_; kb += 16) {
#pragma unroll
    for (int l = 0; l < 2; l++) {
      int idx = tid + l * 256;
      int row = idx >> 2, k4 = (idx & 3) * 4;
      float4 va = *(const float4*)(Ag + (size_t)row * F_ + kb + k4);
      sA[k4 + 0][row] = va.x; sA[k4 + 1][row] = va.y;
      sA[k4 + 2][row] = va.z; sA[k4 + 3][row] = va.w;
      float4 vb = *(const float4*)(Bg + (size_t)row * F_ + kb + k4);
      sB[k4 + 0][row] = vb.x; sB[k4 + 1][row] = vb.y;
      sB[k4 + 2][row] = vb.z; sB[k4 + 3][row] = vb.w;
    }
    __syncthreads();
#pragma unroll
    for (int kk = 0; kk < 16; kk++) {
      float a[8], bb[8];
      *(float4*)&a[0]  = *(const float4*)&sA[kk][ty * 8];
      *(float4*)&a[4]  = *(const float4*)&sA[kk][ty * 8 + 4];
      *(float4*)&bb[0] = *(const float4*)&sB[kk][tx * 8];
      *(float4*)&bb[4] = *(const float4*)&sB[kk][tx * 8 + 4];
#pragma unroll
      for (int i = 0; i < 8; i++)
#pragma unroll
        for (int j = 0; j < 8; j++) acc[i][j] += a[i] * bb[j];
    }
    __syncthreads();
  }
#pragma unroll
  for (int i = 0; i < 8; i++) {
    size_t off = ((size_t)(b * N_ + m0 + ty * 8 + i)) * N_ + n0 + tx * 8;
    float4 o0 = {acc[i][0], acc[i][1], acc[i][2], acc[i][3]};
    float4 o1 = {acc[i][4], acc[i][5], acc[i][6], acc[i][7]};
    *(float4*)(S + off) = o0; *(float4*)(S + off + 4) = o1;
  }
}

// ---------------- row softmax over N=1024, one block per row ----------------
__global__ __launch_bounds__(256) void softmax_row(
    const float* __restrict__ in, float* __restrict__ out) {
  int row = blockIdx.x;
  float4 v = ((const float4*)(in + (size_t)row * N_))[threadIdx.x];
  float m = fmaxf(fmaxf(v.x, v.y), fmaxf(v.z, v.w));
#pragma unroll
  for (int o = 32; o > 0; o >>= 1) m = fmaxf(m, __shfl_down(m, o, 64));
  __shared__ float rmax[4], rsum[4];
  int wave = threadIdx.x >> 6, lane = threadIdx.x & 63;
  if (lane == 0) rmax[wave] = m;
  __syncthreads();
  m = fmaxf(fmaxf(rmax[0], rmax[1]), fmaxf(rmax[2], rmax[3]));
  float e0 = __expf(v.x - m), e1 = __expf(v.y - m);
  float e2 = __expf(v.z - m), e3 = __expf(v.w - m);
  float s = e0 + e1 + e2 + e3;
#pragma unroll
  for (int o = 32; o > 0; o >>= 1) s += __shfl_down(s, o, 64);
  if (lane == 0) rsum[wave] = s;
  __syncthreads();
  s = rsum[0] + rsum[1] + rsum[2] + rsum[3];
  float inv = 1.f / s;
  float4 o4 = {e0 * inv, e1 * inv, e2 * inv, e3 * inv};
  ((float4*)(out + (size_t)row * N_))[threadIdx.x] = o4;
}

// ---------------- row stats: stats[row] = (max, 1/sumexp) ----------------
__global__ __launch_bounds__(256) void row_stats(
    const float* __restrict__ in, float2* __restrict__ stats) {
  int row = blockIdx.x;
  float4 v = ((const float4*)(in + (size_t)row * N_))[threadIdx.x];
  float m = fmaxf(fmaxf(v.x, v.y), fmaxf(v.z, v.w));
#pragma unroll
  for (int o = 32; o > 0; o >>= 1) m = fmaxf(m, __shfl_down(m, o, 64));
  __shared__ float rmax[4], rsum[4];
  int wave = threadIdx.x >> 6, lane = threadIdx.x & 63;
  if (lane == 0) rmax[wave] = m;
  __syncthreads();
  m = fmaxf(fmaxf(rmax[0], rmax[1]), fmaxf(rmax[2], rmax[3]));
  float s = __expf(v.x - m) + __expf(v.y - m) + __expf(v.z - m) + __expf(v.w - m);
#pragma unroll
  for (int o = 32; o > 0; o >>= 1) s += __shfl_down(s, o, 64);
  if (lane == 0) rsum[wave] = s;
  __syncthreads();
  if (threadIdx.x == 0) {
    float tot = rsum[0] + rsum[1] + rsum[2] + rsum[3];
    stats[row] = make_float2(m, 1.f / tot);
  }
}

// ---- r_t partial: part[b][c][t][r] = sum_{s in chunk c} S[b,s,t]*r_s[b,s,r] ----
// EXP variant reads raw Shat + row stats and applies softmax on the fly.
template <bool EXP>
__global__ __launch_bounds__(256) void rt_part_k(
    const float* __restrict__ S, const float2* __restrict__ stats,
    const float* __restrict__ rs, float* __restrict__ part) {
  int b = blockIdx.z, c = blockIdx.y, t0 = blockIdx.x * 256;
  int tid = threadIdx.x;
  int s0 = c * 32;
  __shared__ float rsh[32][16];
  __shared__ float sstat[64];
  if (tid < 128) {
    int srow = tid >> 2, c4 = (tid & 3) * 4;
    float4 v = *(const float4*)(rs + ((size_t)(b * N_ + s0 + srow)) * R_ + c4);
    rsh[srow][c4] = v.x; rsh[srow][c4 + 1] = v.y;
    rsh[srow][c4 + 2] = v.z; rsh[srow][c4 + 3] = v.w;
  } else if (EXP && tid < 192) {
    sstat[tid - 128] = ((const float*)(stats + b * N_ + s0))[tid - 128];
  }
  __syncthreads();
  float acc[16] = {};
  const float* Sp = S + ((size_t)(b * N_ + s0)) * N_ + t0 + tid;
#pragma unroll
  for (int s = 0; s < 32; s++) {
    float sv = Sp[(size_t)s * N_];
    if (EXP) sv = __expf(sv - sstat[2 * s]) * sstat[2 * s + 1];
#pragma unroll
    for (int r = 0; r < 16; r++) acc[r] += sv * rsh[s][r];
  }
  float* o = part + ((size_t)((b * 32 + c) * N_) + t0 + tid) * R_;
  *(float4*)(o + 0)  = *(float4*)&acc[0];
  *(float4*)(o + 4)  = *(float4*)&acc[4];
  *(float4*)(o + 8)  = *(float4*)&acc[8];
  *(float4*)(o + 12) = *(float4*)&acc[12];
}

// ---- r_t reduce over 32 chunks ----
__global__ __launch_bounds__(256) void rt_reduce(
    const float* __restrict__ part, float* __restrict__ rt) {
  int gid = blockIdx.x * 256 + threadIdx.x;   // 16384 float4 outputs
  int b = gid >> 12, tr = gid & 4095;
  const float* p = part + (size_t)b * (32 * N_ * R_) + (size_t)tr * 4;
  float4 acc = {0.f, 0.f, 0.f, 0.f};
#pragma unroll
  for (int c = 0; c < 32; c++) {
    float4 v = *(const float4*)(p + (size_t)c * (N_ * R_));
    acc.x += v.x; acc.y += v.y; acc.z += v.z; acc.w += v.w;
  }
  ((float4*)rt)[gid] = acc;
}

// ---- fused gather + psi2 + @Wm1: P = relu(v@W2s + (gather v)@W2n + b2) @ Wm1 ----
// block = 16 nodes x 16 ch; gather result stays in registers/LDS
__global__ __launch_bounds__(256) void gpsi2p(
    const float* __restrict__ vs, const float* __restrict__ vt,
    const int* __restrict__ csr, const int* __restrict__ offs,
    const float* __restrict__ W2s, const float* __restrict__ W2n,
    const float* __restrict__ b2, const float* __restrict__ Wm1,
    float* __restrict__ Ps, float* __restrict__ Pt) {
  const float* v = blockIdx.y ? vt : vs;
  const int* cs = csr + blockIdx.y * E_;
  const int* of = offs + blockIdx.y * (BN_ + 1);
  float* P = blockIdx.y ? Pt : Ps;
  int col = threadIdx.x & 15, row = threadIdx.x >> 4;
  int node = blockIdx.x * 16 + row;
  int j0 = of[node], j1 = of[node + 1];
  float a0 = 0.f, a1 = 0.f, a2 = 0.f, a3 = 0.f;
  int j = j0;
  for (; j + 3 < j1; j += 4) {
    int s0 = cs[j], s1 = cs[j + 1], s2 = cs[j + 2], s3 = cs[j + 3];
    a0 += v[(size_t)s0 * R_ + col];
    a1 += v[(size_t)s1 * R_ + col];
    a2 += v[(size_t)s2 * R_ + col];
    a3 += v[(size_t)s3 * R_ + col];
  }
  for (; j < j1; j++) a0 += v[(size_t)cs[j] * R_ + col];
  __shared__ float sWs[16][16], sWn[16][16], sWm[16][17];
  __shared__ float sv[16][17], sa[16][17], so[16][17];
  sWs[row][col] = W2s[row * 16 + col];
  sWn[row][col] = W2n[row * 16 + col];
  sWm[row][col] = Wm1[row * 16 + col];
  sv[row][col] = v[(size_t)node * R_ + col];
  sa[row][col] = (a0 + a1) + (a2 + a3);
  __syncthreads();
  float o = b2[col];
#pragma unroll
  for (int k = 0; k < 16; k++) o += sv[row][k] * sWs[k][col] + sa[row][k] * sWn[k][col];
  so[row][col] = fmaxf(o, 0.f);
  __syncthreads();
  float p = 0;
#pragma unroll
  for (int k = 0; k < 16; k++) p += so[row][k] * sWm[k][col];
  P[(size_t)node * R_ + col] = p;
}

// ---- S_hat[b,s,t] += sum_r relu(Ps[b,s,r]-Pt[b,t,r]+bm1[r])*Wm2[r] + bm2 ----
__global__ __launch_bounds__(256) void upd_kernel(
    float* __restrict__ Shat, const float* __restrict__ Ps, const float* __restrict__ Pt,
    const float* __restrict__ bm1, const float* __restrict__ Wm2,
    const float* __restrict__ bm2) {
  int b = blockIdx.z, s0 = blockIdx.y * 4, t0 = blockIdx.x * 256;
  int tid = threadIdx.x;
  __shared__ float pt[256][17];
  __shared__ float ps[4][16];
  __shared__ float sb[16], sw[16];
  for (int i = tid; i < 1024; i += 256) {
    int tr = i >> 2, c = (i & 3) * 4;
    const float4 v = *(const float4*)(Pt + ((size_t)(b * N_ + t0 + tr)) * R_ + c);
    pt[tr][c] = v.x; pt[tr][c + 1] = v.y; pt[tr][c + 2] = v.z; pt[tr][c + 3] = v.w;
  }
  if (tid < 64) ps[tid >> 4][tid & 15] = Ps[((size_t)(b * N_ + s0 + (tid >> 4))) * R_ + (tid & 15)];
  if (tid < 16) { sb[tid] = bm1[tid]; sw[tid] = Wm2[tid]; }
  __syncthreads();
  float bm2v = bm2[0];
  float ptl[16];
#pragma unroll
  for (int r = 0; r < 16; r++) ptl[r] = pt[tid][r];
#pragma unroll
  for (int si = 0; si < 4; si++) {
    size_t off = ((size_t)(b * N_ + s0 + si)) * N_ + t0 + tid;
    float sum = bm2v;
#pragma unroll
    for (int r = 0; r < 16; r++) sum += fmaxf(ps[si][r] - ptl[r] + sb[r], 0.f) * sw[r];
    Shat[off] += sum;
  }
}

extern "C" void kernel_launch(void* const* d_in, const int* in_sizes, int n_in,
                              void* d_out, int out_size, void* d_ws, size_t ws_size,
                              hipStream_t stream) {
  const float* x_s = (const float*)d_in[0];
  const int*   ei_s = (const int*)d_in[1];
  const float* x_t = (const float*)d_in[2];
  const int*   ei_t = (const int*)d_in[3];
  const float* W1s = (const float*)d_in[4];
  const float* W1n = (const float*)d_in[5];
  const float* b1  = (const float*)d_in[6];
  const float* W2s = (const float*)d_in[7];
  const float* W2n = (const float*)d_in[8];
  const float* b2  = (const float*)d_in[9];
  const float* Wm1 = (const float*)d_in[10];
  const float* bm1 = (const float*)d_in[11];
  const float* Wm2 = (const float*)d_in[12];
  const float* bm2 = (const float*)d_in[13];
  const float* r_steps = (const float*)d_in[14];

  float* out = (float*)d_out;
  float* S0 = out;                         // [4,1024,1024]
  float* SL = out + (size_t)B_ * N_ * N_;  // [4,1024,1024]

  float* ws = (float*)d_ws;
  float* agg_s = ws;                       // 524288   (dead after psi1_gemm)
  float* agg_t = ws + 524288;              // 524288   (dead after psi1_gemm)
  float* h_s   = ws + 1048576;             // 524288   (dead after shat_gemm)
  float* h_t   = ws + 1572864;             // 524288   (dead after shat_gemm)
  float* part  = ws;                       // 2097152 floats = 8MB, reuses agg+h region
  float* Shat  = ws + 2097152;             // 4194304
  float* rtb   = ws + 6291456;             // 65536
  float2* stats = (float2*)(ws + 6356992); // 8192 floats (4096 float2)
  float* Ps    = ws + 6488064;             // 65536
  float* Pt    = ws + 6553600;             // 65536
  int* counts  = (int*)(ws + 6619136);     // 8192
  int* cursor  = (int*)(ws + 6627328);     // 8192
  int* offs    = (int*)(ws + 6635520);     // 8194 (2 x 4097)
  int* csr     = (int*)(ws + 6643720);     // 131072

  // ---- CSR build ----
  hipMemsetAsync(counts, 0, 2 * BN_ * sizeof(int), stream);
  hist_k<<<dim3(E_ / 256, 2), 256, 0, stream>>>(ei_s, ei_t, counts);
  csr_scan<<<2, 256, 0, stream>>>(counts, offs, cursor);
  csr_fill<<<dim3(E_ / 256, 2), 256, 0, stream>>>(ei_s, ei_t, cursor, csr);

  // ---- psi1 on both graphs ----
  gather_f<<<dim3(BN_ / 2, 2), 256, 0, stream>>>(x_s, x_t, csr, offs, agg_s, agg_t);
  psi1_gemm<<<dim3(2, 64, 2), 256, 0, stream>>>(x_s, agg_s, x_t, agg_t, W1s, W1n, b1, h_s, h_t);

  // ---- S_hat and S_0 ----
  shat_gemm<<<dim3(8, 8, 4), 256, 0, stream>>>(h_s, h_t, Shat);
  softmax_row<<<B_ * N_, 256, 0, stream>>>(Shat, S0);

  for (int step = 0; step < 2; step++) {
    const float* rs = r_steps + (size_t)step * B_ * N_ * R_;
    if (step == 0) {
      // S_0 already materialized — read probabilities directly
      rt_part_k<false><<<dim3(4, 32, 4), 256, 0, stream>>>(S0, nullptr, rs, part);
    } else {
      // softmax applied on the fly from (max, 1/sum) stats — no S materialization
      row_stats<<<B_ * N_, 256, 0, stream>>>(Shat, stats);
      rt_part_k<true><<<dim3(4, 32, 4), 256, 0, stream>>>(Shat, stats, rs, part);
    }
    rt_reduce<<<64, 256, 0, stream>>>(part, rtb);
    gpsi2p<<<dim3(256, 2), 256, 0, stream>>>(rs, rtb, csr, offs, W2s, W2n, b2, Wm1, Ps, Pt);
    upd_kernel<<<dim3(4, 256, 4), 256, 0, stream>>>(Shat, Ps, Pt, bm1, Wm2, bm2);
  }

  // ---- final S_L ----
  softmax_row<<<B_ * N_, 256, 0, stream>>>(Shat, SL);
}